// Round 6
// baseline (28.511 us; speedup 1.0000x reference)
//
#include <hip/hip_runtime.h>

// Problem constants (match reference)
#define BB 2
#define CC 128
#define NN 4096
#define MM 16384
#define HALF 2048          // points per partial table
#define TS2 4096           // slots per partial table (load 0.5) -> 16KB LDS
#define EMPTYV 0xFFFFFFFFu

// Canonicalize -0.0f -> +0.0f so float== equivalence classes hash identically.
__device__ __forceinline__ unsigned cbits(float v) {
    return __float_as_uint(v == 0.0f ? 0.0f : v);
}
__device__ __forceinline__ unsigned hash3(float x, float y, float z) {
    unsigned h = cbits(x) * 0x9E3779B1u;
    h ^= cbits(y) * 0x85EBCA77u;
    h ^= cbits(z) * 0xC2B2AE3Du;
    h ^= h >> 16;  h *= 0x7FEB352Du;  h ^= h >> 15;
    return h;
}

// ---------------------------------------------------------------------------
// K1: 4 blocks = B batches x 2 halves. Each block builds an exact-match table
// over its 2048-point half in LDS (block-private atomics; slot keeps LOWEST
// index of its float== class via atomicMin -> jnp.argmin tie-break), then
// dumps 16KB coalesced to global. No memset node needed. Half 0 holds indices
// < 2048, so lookup's "A-match wins over B-match" preserves lowest-index.
// ---------------------------------------------------------------------------
__global__ __launch_bounds__(1024) void build_kernel(
    const float* __restrict__ xyz,       // [B,3,N]
    unsigned* __restrict__ tab)          // [B*2, TS2]
{
    __shared__ unsigned ltab[TS2];
    const int b = blockIdx.x >> 1;
    const int h = blockIdx.x & 1;
    const int t = threadIdx.x;

    ((uint4*)ltab)[t] = make_uint4(EMPTYV, EMPTYV, EMPTYV, EMPTYV);  // 1024 uint4
    __syncthreads();

    const float* xb = xyz + (size_t)b * 3 * NN;
    #pragma unroll
    for (int k = 0; k < HALF / 1024; ++k) {        // 2 inserts per thread
        int n = h * HALF + k * 1024 + t;
        float x = xb[n], y = xb[NN + n], z = xb[2 * NN + n];
        unsigned slot = hash3(x, y, z) & (TS2 - 1);
        while (true) {
            unsigned old = atomicCAS(&ltab[slot], EMPTYV, (unsigned)n);
            if (old == EMPTYV) break;
            if (xb[old] == x && xb[NN + old] == y && xb[2 * NN + old] == z) {
                atomicMin(&ltab[slot], (unsigned)n);
                break;
            }
            slot = (slot + 1) & (TS2 - 1);
        }
    }
    __syncthreads();

    ((uint4*)(tab + (size_t)blockIdx.x * TS2))[t] = ((uint4*)ltab)[t];
}

// ---------------------------------------------------------------------------
// K2: 1024 blocks x 256 threads. Block = (b, c-group of 16, m-group of 256).
// Phase 1: every thread looks up ONE anchor (probe half-table A, then B only
// if A missed; verify coords with float==). c-group 0 blocks also copy the
// xyz_anchor passthrough slice. Phase 2: gather/store the 16 x 256 tile with
// wave-contiguous 1KB row segments (full L2 lines, no cross-block sharing).
// ---------------------------------------------------------------------------
__global__ __launch_bounds__(256) void lookup_gather_kernel(
    const float* __restrict__ xyz,       // [B,3,N]
    const float* __restrict__ feature,   // [B,C,N]
    const float* __restrict__ anchor,    // [B,3,M]
    const unsigned* __restrict__ tab,    // [B*2, TS2]
    float* __restrict__ out0,            // [B,3,M]
    float* __restrict__ out1)            // [B,C,M]
{
    __shared__ unsigned sel[256];

    const int blk  = blockIdx.x;
    const int b    = blk >> 9;                   // 512 blocks per batch
    const int cg   = (blk >> 6) & 7;             // c-group: 8 x 16 channels
    const int mg   = blk & 63;                   // m-group: 64 x 256 anchors
    const int m0   = mg * 256;
    const int c0   = cg * 16;
    const int t    = threadIdx.x;

    const float* ap = anchor + (size_t)b * 3 * MM;
    const float* xb = xyz + (size_t)b * 3 * NN;

    // ---- phase 1a: one lookup per thread ----
    {
        const int m = m0 + t;
        const float a0 = ap[m], a1 = ap[MM + m], a2 = ap[2 * MM + m];
        const unsigned h0 = hash3(a0, a1, a2);
        const unsigned* tA = tab + (size_t)(b * 2 + 0) * TS2;
        const unsigned* tB = tab + (size_t)(b * 2 + 1) * TS2;
        unsigned res = EMPTYV;
        unsigned slot = h0 & (TS2 - 1);
        while (true) {                            // probe half A (lower indices)
            unsigned v = tA[slot];
            if (v == EMPTYV) break;
            if (xb[v] == a0 && xb[NN + v] == a1 && xb[2 * NN + v] == a2) { res = v; break; }
            slot = (slot + 1) & (TS2 - 1);
        }
        if (res == EMPTYV) {
            slot = h0 & (TS2 - 1);
            while (true) {                        // probe half B
                unsigned v = tB[slot];
                if (v == EMPTYV) break;
                if (xb[v] == a0 && xb[NN + v] == a1 && xb[2 * NN + v] == a2) { res = v; break; }
                slot = (slot + 1) & (TS2 - 1);
            }
        }
        sel[t] = res;
    }

    // ---- phase 1b: passthrough (c-group 0 only): 3 rows x 64 float4 ----
    if (cg == 0 && t < 192) {
        int d = t >> 6, l = t & 63;
        ((float4*)(out0 + (size_t)b * 3 * MM + (size_t)d * MM + m0))[l] =
            ((const float4*)(ap + (size_t)d * MM + m0))[l];
    }
    __syncthreads();

    // ---- phase 2: gather/store 16 rows x 256 m; wave w owns rows w+4k ----
    const float* fb = feature + (size_t)b * CC * NN;
    float* ob = out1 + (size_t)b * CC * MM + (size_t)c0 * MM + m0;
    const int w = t >> 6, l = t & 63;
    #pragma unroll
    for (int k = 0; k < 4; ++k) {
        const int r = k * 4 + w;
        const float* frow = fb + (size_t)(c0 + r) * NN;
        uint4 s4 = ((uint4*)sel)[l];
        float4 v;
        v.x = (s4.x < NN) ? frow[s4.x] : 0.0f;
        v.y = (s4.y < NN) ? frow[s4.y] : 0.0f;
        v.z = (s4.z < NN) ? frow[s4.z] : 0.0f;
        v.w = (s4.w < NN) ? frow[s4.w] : 0.0f;
        ((float4*)(ob + (size_t)r * MM))[l] = v;
    }
}

extern "C" void kernel_launch(void* const* d_in, const int* in_sizes, int n_in,
                              void* d_out, int out_size, void* d_ws, size_t ws_size,
                              hipStream_t stream) {
    const float* xyz    = (const float*)d_in[0];  // [B,3,N]
    const float* feat   = (const float*)d_in[1];  // [B,C,N]
    const float* anchor = (const float*)d_in[2];  // [B,3,M]

    float* out0 = (float*)d_out;                  // [B,3,M] passthrough
    float* out1 = out0 + BB * 3 * MM;             // [B,C,M]

    unsigned* tab = (unsigned*)d_ws;              // [B*2, TS2] = 64KB

    build_kernel<<<BB * 2, 1024, 0, stream>>>(xyz, tab);
    lookup_gather_kernel<<<BB * 8 * 64, 256, 0, stream>>>(xyz, feat, anchor, tab, out0, out1);
}